// Round 1
// baseline (2456.393 us; speedup 1.0000x reference)
//
#include <hip/hip_runtime.h>
#include <math.h>

#define D_MCB   16000
#define NBATCH  32
#define SEQ     50
#define CDIM    2048
#define NPOS    49
#define NC1     512
#define NOUT    3000
#define K1T     512   // threads for CBP/FFT kernels

// ---------------- complex helpers ----------------
struct cpx { float re, im; };
__device__ __forceinline__ cpx cadd(cpx a, cpx b){ return {a.re+b.re, a.im+b.im}; }
__device__ __forceinline__ cpx csub(cpx a, cpx b){ return {a.re-b.re, a.im-b.im}; }
__device__ __forceinline__ cpx cmul(cpx a, cpx b){ return {a.re*b.re - a.im*b.im, a.re*b.im + a.im*b.re}; }
// a * conj(b)
__device__ __forceinline__ cpx cmulj(cpx a, cpx b){ return {a.re*b.re + a.im*b.im, a.im*b.re - a.re*b.im}; }

// base-5 3-digit reversal (involution), r < 125
__device__ __forceinline__ int dr5i(int r){
  int d0 = r % 5; int q = r / 5; int d1 = q % 5; int d2 = q / 5;
  return d0*25 + d1*5 + d2;
}
// 7-bit reversal (involution)
__device__ __forceinline__ int br7i(int x){ return (int)(__brev((unsigned)x) >> 25); }

// 5-point DFT. sgn=+1: forward (W5 = e^{-2pi i/5}); sgn=-1: inverse (conjugate).
__device__ __forceinline__ void dft5(cpx x0, cpx x1, cpx x2, cpx x3, cpx x4, float sgn,
                                     cpx& y0, cpx& y1, cpx& y2, cpx& y3, cpx& y4) {
  const float C1 = 0.30901699437494745f, S1 = 0.9510565162951535f;
  const float C2 = -0.8090169943749473f, S2 = 0.5877852522924731f;
  cpx t1 = cadd(x1, x4), t2 = cadd(x2, x3);
  cpx t3 = csub(x1, x4), t4 = csub(x2, x3);
  y0 = {x0.re + t1.re + t2.re, x0.im + t1.im + t2.im};
  cpx m1 = {x0.re + C1*t1.re + C2*t2.re, x0.im + C1*t1.im + C2*t2.im};
  cpx m2 = {x0.re + C2*t1.re + C1*t2.re, x0.im + C2*t1.im + C1*t2.im};
  cpx u1 = {S1*t3.re + S2*t4.re, S1*t3.im + S2*t4.im};
  cpx u2 = {S2*t3.re - S1*t4.re, S2*t3.im - S1*t4.im};
  y1 = {m1.re + sgn*u1.im, m1.im - sgn*u1.re};  // m1 -+ i*u1
  y4 = {m1.re - sgn*u1.im, m1.im + sgn*u1.re};
  y2 = {m2.re + sgn*u2.im, m2.im - sgn*u2.re};
  y3 = {m2.re - sgn*u2.im, m2.im + sgn*u2.re};
}

// ---------------- FFT-16000 = 125 x 128 four-step, in LDS ----------------
// Layout: z[n], n = n1*128 + n2  (n1<125 "column index", n2<128).
// Stage A: 128 independent FFT-125 over n1 (radix-5 DIF, digit-reversed out).
// Stage B: per-element twiddle W16000^(n2 * k1), k1 = dr5(row).
// Stage C: 125 independent FFT-128 over n2 (radix-2 DIF, bit-reversed out).
// Spectral element (k1 + 125*k2) ends at LDS pos dr5(k1)*128 + br7(k2).

template<int M, bool FWD>
__device__ void r5_stage(float2* z, const float2* w125s, int tid, int nthr) {
  const int mStep = M/5;
  const int st = mStep*128;
  for (int bf = tid; bf < 3200; bf += nthr) {
    int col = bf & 127, t = bf >> 7;           // t < 25
    int blk = t / mStep, j = t - blk*mStep;
    int base = (blk*M + j)*128 + col;
    float2 v;
    v = z[base];        cpx x0 = {v.x, v.y};
    v = z[base+st];     cpx x1 = {v.x, v.y};
    v = z[base+2*st];   cpx x2 = {v.x, v.y};
    v = z[base+3*st];   cpx x3 = {v.x, v.y};
    v = z[base+4*st];   cpx x4 = {v.x, v.y};
    cpx y0,y1,y2,y3,y4;
    if (FWD) {
      dft5(x0,x1,x2,x3,x4, 1.f, y0,y1,y2,y3,y4);
      if (M > 5) {
        const int fac = 125/M;
        float2 wa = w125s[j*fac], wb = w125s[2*j*fac], wc = w125s[3*j*fac], wd = w125s[4*j*fac];
        y1 = cmul(y1, {wa.x, wa.y}); y2 = cmul(y2, {wb.x, wb.y});
        y3 = cmul(y3, {wc.x, wc.y}); y4 = cmul(y4, {wd.x, wd.y});
      }
    } else {
      if (M > 5) {
        const int fac = 125/M;
        float2 wa = w125s[j*fac], wb = w125s[2*j*fac], wc = w125s[3*j*fac], wd = w125s[4*j*fac];
        x1 = cmulj(x1, {wa.x, wa.y}); x2 = cmulj(x2, {wb.x, wb.y});
        x3 = cmulj(x3, {wc.x, wc.y}); x4 = cmulj(x4, {wd.x, wd.y});
      }
      dft5(x0,x1,x2,x3,x4, -1.f, y0,y1,y2,y3,y4);
    }
    z[base]      = make_float2(y0.re, y0.im);
    z[base+st]   = make_float2(y1.re, y1.im);
    z[base+2*st] = make_float2(y2.re, y2.im);
    z[base+3*st] = make_float2(y3.re, y3.im);
    z[base+4*st] = make_float2(y4.re, y4.im);
  }
}

template<int M, bool FWD>
__device__ void r2_stage(float2* z, const float2* w128s, int tid, int nthr) {
  const int hStep = M/2;
  for (int bf = tid; bf < 8000; bf += nthr) {
    int row = bf >> 6, t = bf & 63;
    int blk = t / hStep, j = t - blk*hStep;
    int p1 = row*128 + blk*M + j, p2 = p1 + hStep;
    float2 va = z[p1], vb = z[p2];
    cpx a = {va.x, va.y}, b = {vb.x, vb.y};
    float2 wf = w128s[j*(128/M)];
    cpx w = {wf.x, wf.y};
    if (FWD) {
      cpx s = cadd(a,b);
      cpx d = cmul(csub(a,b), w);
      z[p1] = make_float2(s.re, s.im);
      z[p2] = make_float2(d.re, d.im);
    } else {
      cpx tt = cmulj(b, w);
      cpx s = cadd(a,tt), d = csub(a,tt);
      z[p1] = make_float2(s.re, s.im);
      z[p2] = make_float2(d.re, d.im);
    }
  }
}

template<bool FWD>
__device__ void twiddle_pass(float2* z, int tid, int nthr) {
  for (int e = tid; e < 16000; e += nthr) {
    int row = e >> 7, col = e & 127;
    int k1 = dr5i(row);
    int m = col * k1;                          // < 16000, no mod needed
    float ph = (float)m * (6.283185307179586f / 16000.f);
    float s, c;
    __sincosf(ph, &s, &c);
    cpx w = {c, FWD ? -s : s};
    float2 v2 = z[e];
    cpx v = cmul({v2.x, v2.y}, w);
    z[e] = make_float2(v.re, v.im);
  }
}

// Z = FFT(sk1 + i*sk2) in permuted layout. Extract F1,F2 per conjugate pair,
// write Y = F1*F2 back (conjugate-symmetric), still permuted.
__device__ void spectral_multiply(float2* z, int tid, int nthr) {
  for (int idx = tid; idx < 8001; idx += nthr) {
    int k1, k2, k1p, k2p;
    if (idx < 7936) { k1 = 1 + (idx >> 7); k2 = idx & 127; k1p = 125 - k1; k2p = 127 - k2; }
    else            { k1 = 0; k2 = idx - 7936; k1p = 0;    k2p = (128 - k2) & 127; }
    int pos  = dr5i(k1)*128  + br7i(k2);
    int posp = dr5i(k1p)*128 + br7i(k2p);
    float2 vk = z[pos], vm = z[posp];
    cpx Zk = {vk.x, vk.y}, Zm = {vm.x, vm.y};
    cpx F1 = {0.5f*(Zk.re + Zm.re), 0.5f*(Zk.im - Zm.im)};
    cpx F2 = {0.5f*(Zk.im + Zm.im), 0.5f*(Zm.re - Zk.re)};
    cpx Y = cmul(F1, F2);
    z[pos]  = make_float2(Y.re,  Y.im);
    z[posp] = make_float2(Y.re, -Y.im);   // self-pairs: Y.im == 0, benign
  }
}

__device__ void fft_convolve(float2* z, const float2* w128s, const float2* w125s,
                             int tid, int nthr) {
  r5_stage<125,true>(z,w125s,tid,nthr); __syncthreads();
  r5_stage<25, true>(z,w125s,tid,nthr); __syncthreads();
  r5_stage<5,  true>(z,w125s,tid,nthr); __syncthreads();
  twiddle_pass<true>(z,tid,nthr);       __syncthreads();
  r2_stage<128,true>(z,w128s,tid,nthr); __syncthreads();
  r2_stage<64, true>(z,w128s,tid,nthr); __syncthreads();
  r2_stage<32, true>(z,w128s,tid,nthr); __syncthreads();
  r2_stage<16, true>(z,w128s,tid,nthr); __syncthreads();
  r2_stage<8,  true>(z,w128s,tid,nthr); __syncthreads();
  r2_stage<4,  true>(z,w128s,tid,nthr); __syncthreads();
  r2_stage<2,  true>(z,w128s,tid,nthr); __syncthreads();
  spectral_multiply(z,tid,nthr);        __syncthreads();
  r2_stage<2,  false>(z,w128s,tid,nthr); __syncthreads();
  r2_stage<4,  false>(z,w128s,tid,nthr); __syncthreads();
  r2_stage<8,  false>(z,w128s,tid,nthr); __syncthreads();
  r2_stage<16, false>(z,w128s,tid,nthr); __syncthreads();
  r2_stage<32, false>(z,w128s,tid,nthr); __syncthreads();
  r2_stage<64, false>(z,w128s,tid,nthr); __syncthreads();
  r2_stage<128,false>(z,w128s,tid,nthr); __syncthreads();
  twiddle_pass<false>(z,tid,nthr);       __syncthreads();
  r5_stage<5,  false>(z,w125s,tid,nthr); __syncthreads();
  r5_stage<25, false>(z,w125s,tid,nthr); __syncthreads();
  r5_stage<125,false>(z,w125s,tid,nthr); __syncthreads();
  // result: 16000 * (sk1 circconv sk2) in z[n].x, natural order
}

__device__ __forceinline__ float block_sum(float v, float* red, int tid, int nthr) {
  #pragma unroll
  for (int off = 32; off > 0; off >>= 1) v += __shfl_down(v, off);
  if ((tid & 63) == 0) red[tid >> 6] = v;
  __syncthreads();
  if (tid == 0) {
    float s = 0.f;
    for (int w = 0; w < (nthr >> 6); ++w) s += red[w];
    red[0] = s;
  }
  __syncthreads();
  return red[0];
}

__device__ __forceinline__ void init_twiddle_tables(float2* w128s, float2* w125s, int tid) {
  if (tid < 64) {
    float s, c; sincosf((float)tid * (6.283185307179586f/128.f), &s, &c);
    w128s[tid] = make_float2(c, -s);
  } else if (tid < 164) {
    int t = tid - 64;
    float s, c; sincosf((float)t * (6.283185307179586f/125.f), &s, &c);
    w125s[t] = make_float2(c, -s);
  }
}

// ---------------- K0: avgpool(txt) -> txt_p (32,2048) ----------------
__global__ void k_txtpool(const float* __restrict__ txt, float* __restrict__ txtp) {
  int idx = blockIdx.x*256 + threadIdx.x;      // exactly 32*2048 threads
  int b = idx >> 11, w = idx & 2047;
  const float* t = txt + (size_t)b*SEQ*CDIM;
  float s = 0.f;
  #pragma unroll
  for (int r = 0; r < 2; ++r)
    #pragma unroll
    for (int dc = -1; dc <= 1; ++dc) {
      int c = w + dc;
      if (c >= 0 && c < CDIM) s += t[r*CDIM + c];
    }
  txtp[idx] = s * (1.0f/9.0f);
}

// ---------------- K1: CBP #1 per (b,p) row; writes signed_sqrt values + row norm ---
__global__ void __launch_bounds__(K1T) k_cbp1(
    const float* __restrict__ txtp, const float* __restrict__ img,
    const int* __restrict__ h1a, const int* __restrict__ s1a,
    const int* __restrict__ h2a, const int* __restrict__ s2a,
    float* __restrict__ ss1, float* __restrict__ norm1) {
  __shared__ float2 zbuf[16000];
  __shared__ float2 w128s[64];
  __shared__ float2 w125s[100];
  __shared__ float red[8];
  int tid = threadIdx.x;
  int r = blockIdx.x;
  int b = r / NPOS, p = r % NPOS;
  init_twiddle_tables(w128s, w125s, tid);
  for (int n = tid; n < 16000; n += K1T) zbuf[n] = make_float2(0.f, 0.f);
  __syncthreads();
  // scatter count sketches: sk1 -> .x, sk2 -> .y
  const float* tp = txtp + b*CDIM;
  for (int i = tid; i < CDIM; i += K1T) {
    int idx = (49*i + p) & (CDIM-1);
    float a = (float)s1a[i] * tp[idx];
    atomicAdd(&zbuf[h1a[i]].x, a);
    float bb = (float)s2a[i] * img[((size_t)b*CDIM + i)*NPOS + p];
    atomicAdd(&zbuf[h2a[i]].y, bb);
  }
  __syncthreads();
  fft_convolve(zbuf, w128s, w125s, tid, K1T);
  // epilogue: scale 1/16000, signed sqrt, store, norm
  const float inv = 1.0f/16000.0f;
  float sumsq = 0.f;
  for (int n = tid; n < 16000; n += K1T) {
    float v = zbuf[n].x * inv;
    float o = copysignf(sqrtf(fabsf(v)), v);
    ss1[(size_t)r*D_MCB + n] = o;
    sumsq += o*o;
  }
  float tot = block_sum(sumsq, red, tid, K1T);
  if (tid == 0) norm1[r] = fmaxf(sqrtf(tot), 1e-12f);
}

// ---------------- K2: conv1 GEMM (1568x16000)x(512x16000)^T, /norm, +bias, relu ----
#define GBM 64
#define GBN 64
#define GBK 16
#define LDT 20   // padded LDS row stride
__global__ void __launch_bounds__(256) k_conv1(
    const float* __restrict__ ss1, const float* __restrict__ norm1,
    const float* __restrict__ w1, const float* __restrict__ b1,
    float* __restrict__ out1) {
  __shared__ float As[GBM*LDT];
  __shared__ float Bs[GBN*LDT];
  int tid = threadIdx.x;
  int mt = blockIdx.x, nt = blockIdx.y;
  int m0 = mt*GBM, n0 = nt*GBN;
  int tx = tid & 15, ty = tid >> 4;
  int lr = tid >> 2, lc = (tid & 3)*4;
  int arow = m0 + lr; if (arow > 1567) arow = 1567;
  const float* Ag = ss1 + (size_t)arow*D_MCB + lc;
  const float* Bg = w1  + (size_t)(n0 + lr)*D_MCB + lc;
  float acc[4][4] = {};
  for (int k0 = 0; k0 < D_MCB; k0 += GBK) {
    float4 av = *(const float4*)(Ag + k0);
    float4 bv = *(const float4*)(Bg + k0);
    *(float4*)&As[lr*LDT + lc] = av;
    *(float4*)&Bs[lr*LDT + lc] = bv;
    __syncthreads();
    #pragma unroll
    for (int kq = 0; kq < 4; ++kq) {
      float4 a[4], bq[4];
      #pragma unroll
      for (int i = 0; i < 4; ++i) a[i]  = *(float4*)&As[(ty*4+i)*LDT + kq*4];
      #pragma unroll
      for (int j = 0; j < 4; ++j) bq[j] = *(float4*)&Bs[(tx*4+j)*LDT + kq*4];
      #pragma unroll
      for (int i = 0; i < 4; ++i)
        #pragma unroll
        for (int j = 0; j < 4; ++j)
          acc[i][j] += a[i].x*bq[j].x + a[i].y*bq[j].y + a[i].z*bq[j].z + a[i].w*bq[j].w;
    }
    __syncthreads();
  }
  #pragma unroll
  for (int i = 0; i < 4; ++i) {
    int m = m0 + ty*4 + i;
    if (m < 1568) {
      float nrm = norm1[m];
      #pragma unroll
      for (int j = 0; j < 4; ++j) {
        int n = n0 + tx*4 + j;
        float v = acc[i][j]/nrm + b1[n];
        out1[(size_t)m*NC1 + n] = fmaxf(v, 0.f);
      }
    }
  }
}

// ---------------- K3: conv2 + softmax(49) + attention-weighted pooling -> res -------
__global__ void __launch_bounds__(256) k_attn(
    const float* __restrict__ out1, const float* __restrict__ w2,
    const float* __restrict__ b2, const float* __restrict__ img,
    float* __restrict__ res) {
  __shared__ float s_lds[NPOS];
  __shared__ float att[NPOS];
  int b = blockIdx.x, tid = threadIdx.x;
  int wave = tid >> 6, lane = tid & 63;
  for (int p = wave; p < NPOS; p += 4) {
    const float* row = out1 + (size_t)(b*NPOS + p)*NC1;
    float acc = 0.f;
    for (int o = lane; o < NC1; o += 64) acc += row[o]*w2[o];
    #pragma unroll
    for (int off = 32; off > 0; off >>= 1) acc += __shfl_down(acc, off);
    if (lane == 0) s_lds[p] = acc + b2[0];
  }
  __syncthreads();
  if (tid < 64) {
    float v = (tid < NPOS) ? s_lds[tid] : -INFINITY;
    float mx = v;
    #pragma unroll
    for (int off = 32; off > 0; off >>= 1) mx = fmaxf(mx, __shfl_xor(mx, off));
    float e = (tid < NPOS) ? expf(v - mx) : 0.f;
    float se = e;
    #pragma unroll
    for (int off = 32; off > 0; off >>= 1) se += __shfl_xor(se, off);
    if (tid < NPOS) att[tid] = e / se;
  }
  __syncthreads();
  // faithful torch .view: img_r[b,p,c] = flat[b*(49*2048) + p*2048 + c]
  const float* ib = img + (size_t)b*CDIM*NPOS;
  for (int c = tid; c < CDIM; c += 256) {
    float acc = 0.f;
    for (int p = 0; p < NPOS; ++p) acc += att[p]*ib[(size_t)p*CDIM + c];
    res[b*CDIM + c] = acc;
  }
}

// ---------------- K4: CBP #2 (32 rows), signed_sqrt + norm ----------------
__global__ void __launch_bounds__(K1T) k_cbp2(
    const float* __restrict__ txtp, const float* __restrict__ res,
    const int* __restrict__ h1b, const int* __restrict__ s1b,
    const int* __restrict__ h2b, const int* __restrict__ s2b,
    float* __restrict__ fin_ss, float* __restrict__ norm2) {
  __shared__ float2 zbuf[16000];
  __shared__ float2 w128s[64];
  __shared__ float2 w125s[100];
  __shared__ float red[8];
  int tid = threadIdx.x;
  int b = blockIdx.x;
  init_twiddle_tables(w128s, w125s, tid);
  for (int n = tid; n < 16000; n += K1T) zbuf[n] = make_float2(0.f, 0.f);
  __syncthreads();
  for (int i = tid; i < CDIM; i += K1T) {
    atomicAdd(&zbuf[h1b[i]].x, (float)s1b[i] * txtp[b*CDIM + i]);
    atomicAdd(&zbuf[h2b[i]].y, (float)s2b[i] * res[b*CDIM + i]);
  }
  __syncthreads();
  fft_convolve(zbuf, w128s, w125s, tid, K1T);
  const float inv = 1.0f/16000.0f;
  float sumsq = 0.f;
  for (int n = tid; n < 16000; n += K1T) {
    float v = zbuf[n].x * inv;
    float o = copysignf(sqrtf(fabsf(v)), v);
    fin_ss[(size_t)b*D_MCB + n] = o;
    sumsq += o*o;
  }
  float tot = block_sum(sumsq, red, tid, K1T);
  if (tid == 0) norm2[b] = fmaxf(sqrtf(tot), 1e-12f);
}

// ---------------- K5: final linear (32x16000)x(3000x16000)^T /norm + bias ----------
__global__ void k_out_init(const float* __restrict__ lin2b, float* __restrict__ out) {
  int i = blockIdx.x*256 + threadIdx.x;
  if (i < NBATCH*NOUT) out[i] = lin2b[i % NOUT];
}

#define K5BK 40
__global__ void __launch_bounds__(256) k_lin2(
    const float* __restrict__ fin_ss, const float* __restrict__ norm2,
    const float* __restrict__ w, float* __restrict__ out) {
  __shared__ float Ws[K5BK*128];   // [kk][o]
  __shared__ float Fs[32*44];      // [b][kk], padded
  int tid = threadIdx.x;
  int nt = blockIdx.x;             // 24 tiles of 128 outputs
  int kc = blockIdx.y;             // 8 chunks of 2000
  int o0 = nt*128;
  int kb = kc*2000;
  int tb = tid >> 5, to = tid & 31;
  float acc[4][4] = {};
  for (int ks = 0; ks < 2000; ks += K5BK) {
    for (int q = tid; q < 1280; q += 256) {
      int wrow = q / 10, wq = q % 10;
      int orow = o0 + wrow; if (orow > NOUT-1) orow = NOUT-1;
      float4 v = *(const float4*)(w + (size_t)orow*D_MCB + kb + ks + wq*4);
      Ws[(wq*4+0)*128 + wrow] = v.x;
      Ws[(wq*4+1)*128 + wrow] = v.y;
      Ws[(wq*4+2)*128 + wrow] = v.z;
      Ws[(wq*4+3)*128 + wrow] = v.w;
    }
    for (int q = tid; q < 320; q += 256) {
      int fr = q / 10, fq = q % 10;
      float4 v = *(const float4*)(fin_ss + (size_t)fr*D_MCB + kb + ks + fq*4);
      *(float4*)&Fs[fr*44 + fq*4] = v;
    }
    __syncthreads();
    #pragma unroll 8
    for (int kk = 0; kk < K5BK; ++kk) {
      float fv[4];
      #pragma unroll
      for (int i = 0; i < 4; ++i) fv[i] = Fs[(tb*4+i)*44 + kk];
      float4 wv = *(float4*)&Ws[kk*128 + to*4];
      #pragma unroll
      for (int i = 0; i < 4; ++i) {
        acc[i][0] += fv[i]*wv.x; acc[i][1] += fv[i]*wv.y;
        acc[i][2] += fv[i]*wv.z; acc[i][3] += fv[i]*wv.w;
      }
    }
    __syncthreads();
  }
  #pragma unroll
  for (int i = 0; i < 4; ++i) {
    int bb = tb*4 + i;
    float nrm = norm2[bb];
    #pragma unroll
    for (int j = 0; j < 4; ++j) {
      int o = o0 + to*4 + j;
      if (o < NOUT) atomicAdd(&out[bb*NOUT + o], acc[i][j]/nrm);
    }
  }
}

// ---------------- launch ----------------
extern "C" void kernel_launch(void* const* d_in, const int* in_sizes, int n_in,
                              void* d_out, int out_size, void* d_ws, size_t ws_size,
                              hipStream_t stream) {
  (void)in_sizes; (void)n_in; (void)out_size; (void)ws_size;
  const float* txt    = (const float*)d_in[0];
  const float* img    = (const float*)d_in[1];
  const float* conv1w = (const float*)d_in[2];
  const float* conv1b = (const float*)d_in[3];
  const float* conv2w = (const float*)d_in[4];
  const float* conv2b = (const float*)d_in[5];
  const float* lin2w  = (const float*)d_in[6];
  const float* lin2b  = (const float*)d_in[7];
  const int* h1a = (const int*)d_in[8];  const int* s1a = (const int*)d_in[9];
  const int* h2a = (const int*)d_in[10]; const int* s2a = (const int*)d_in[11];
  const int* h1b = (const int*)d_in[12]; const int* s1b = (const int*)d_in[13];
  const int* h2b = (const int*)d_in[14]; const int* s2b = (const int*)d_in[15];
  float* out = (float*)d_out;
  char* ws = (char*)d_ws;
  // workspace layout (16B aligned), total ~101.2 MiB
  float* txtp   = (float*)(ws + 0);          // 262,144 B
  float* norm1  = (float*)(ws + 262144);     //   6,272 B
  float* resb   = (float*)(ws + 268416);     // 262,144 B
  float* norm2  = (float*)(ws + 530560);     //     128 B
  float* fin_ss = (float*)(ws + 530688);     // 2,048,000 B
  float* out1   = (float*)(ws + 2578688);    // 3,211,264 B
  float* ss1    = (float*)(ws + 5789952);    // 100,352,000 B

  k_txtpool<<<dim3(256), dim3(256), 0, stream>>>(txt, txtp);
  k_cbp1<<<dim3(NBATCH*NPOS), dim3(K1T), 0, stream>>>(txtp, img, h1a, s1a, h2a, s2a, ss1, norm1);
  k_conv1<<<dim3(25, 8), dim3(256), 0, stream>>>(ss1, norm1, conv1w, conv1b, out1);
  k_attn<<<dim3(NBATCH), dim3(256), 0, stream>>>(out1, conv2w, conv2b, img, resb);
  k_cbp2<<<dim3(NBATCH), dim3(K1T), 0, stream>>>(txtp, resb, h1b, s1b, h2b, s2b, fin_ss, norm2);
  k_out_init<<<dim3((NBATCH*NOUT + 255)/256), dim3(256), 0, stream>>>(lin2b, out);
  k_lin2<<<dim3(24, 8), dim3(256), 0, stream>>>(fin_ss, norm2, lin2w, out);
}

// Round 2
// 1192.276 us; speedup vs baseline: 2.0603x; 2.0603x over previous
//
#include <hip/hip_runtime.h>
#include <hip/hip_bf16.h>
#include <math.h>

#define D_MCB   16000
#define NBATCH  32
#define SEQ     50
#define CDIM    2048
#define NPOS    49
#define NC1     512
#define NOUT    3000
#define K1T     512   // threads for CBP/FFT kernels

typedef __attribute__((ext_vector_type(8))) short short8;
typedef __attribute__((ext_vector_type(4))) float f32x4;

// ---------------- complex helpers ----------------
struct cpx { float re, im; };
__device__ __forceinline__ cpx cadd(cpx a, cpx b){ return {a.re+b.re, a.im+b.im}; }
__device__ __forceinline__ cpx csub(cpx a, cpx b){ return {a.re-b.re, a.im-b.im}; }
__device__ __forceinline__ cpx cmul(cpx a, cpx b){ return {a.re*b.re - a.im*b.im, a.re*b.im + a.im*b.re}; }
// a * conj(b)
__device__ __forceinline__ cpx cmulj(cpx a, cpx b){ return {a.re*b.re + a.im*b.im, a.im*b.re - a.re*b.im}; }

// base-5 3-digit reversal (involution), r < 125
__device__ __forceinline__ int dr5i(int r){
  int d0 = r % 5; int q = r / 5; int d1 = q % 5; int d2 = q / 5;
  return d0*25 + d1*5 + d2;
}
// 7-bit reversal (involution)
__device__ __forceinline__ int br7i(int x){ return (int)(__brev((unsigned)x) >> 25); }

// 5-point DFT. sgn=+1: forward (W5 = e^{-2pi i/5}); sgn=-1: inverse (conjugate).
__device__ __forceinline__ void dft5(cpx x0, cpx x1, cpx x2, cpx x3, cpx x4, float sgn,
                                     cpx& y0, cpx& y1, cpx& y2, cpx& y3, cpx& y4) {
  const float C1 = 0.30901699437494745f, S1 = 0.9510565162951535f;
  const float C2 = -0.8090169943749473f, S2 = 0.5877852522924731f;
  cpx t1 = cadd(x1, x4), t2 = cadd(x2, x3);
  cpx t3 = csub(x1, x4), t4 = csub(x2, x3);
  y0 = {x0.re + t1.re + t2.re, x0.im + t1.im + t2.im};
  cpx m1 = {x0.re + C1*t1.re + C2*t2.re, x0.im + C1*t1.im + C2*t2.im};
  cpx m2 = {x0.re + C2*t1.re + C1*t2.re, x0.im + C2*t1.im + C1*t2.im};
  cpx u1 = {S1*t3.re + S2*t4.re, S1*t3.im + S2*t4.im};
  cpx u2 = {S2*t3.re - S1*t4.re, S2*t3.im - S1*t4.im};
  y1 = {m1.re + sgn*u1.im, m1.im - sgn*u1.re};  // m1 -+ i*u1
  y4 = {m1.re - sgn*u1.im, m1.im + sgn*u1.re};
  y2 = {m2.re + sgn*u2.im, m2.im - sgn*u2.re};
  y3 = {m2.re - sgn*u2.im, m2.im + sgn*u2.re};
}

// ---------------- FFT-16000 = 125 x 128 four-step, in LDS ----------------
template<int M, bool FWD>
__device__ void r5_stage(float2* z, const float2* w125s, int tid, int nthr) {
  const int mStep = M/5;
  const int st = mStep*128;
  for (int bf = tid; bf < 3200; bf += nthr) {
    int col = bf & 127, t = bf >> 7;           // t < 25
    int blk = t / mStep, j = t - blk*mStep;
    int base = (blk*M + j)*128 + col;
    float2 v;
    v = z[base];        cpx x0 = {v.x, v.y};
    v = z[base+st];     cpx x1 = {v.x, v.y};
    v = z[base+2*st];   cpx x2 = {v.x, v.y};
    v = z[base+3*st];   cpx x3 = {v.x, v.y};
    v = z[base+4*st];   cpx x4 = {v.x, v.y};
    cpx y0,y1,y2,y3,y4;
    if (FWD) {
      dft5(x0,x1,x2,x3,x4, 1.f, y0,y1,y2,y3,y4);
      if (M > 5) {
        const int fac = 125/M;
        float2 wa = w125s[j*fac], wb = w125s[2*j*fac], wc = w125s[3*j*fac], wd = w125s[4*j*fac];
        y1 = cmul(y1, {wa.x, wa.y}); y2 = cmul(y2, {wb.x, wb.y});
        y3 = cmul(y3, {wc.x, wc.y}); y4 = cmul(y4, {wd.x, wd.y});
      }
    } else {
      if (M > 5) {
        const int fac = 125/M;
        float2 wa = w125s[j*fac], wb = w125s[2*j*fac], wc = w125s[3*j*fac], wd = w125s[4*j*fac];
        x1 = cmulj(x1, {wa.x, wa.y}); x2 = cmulj(x2, {wb.x, wb.y});
        x3 = cmulj(x3, {wc.x, wc.y}); x4 = cmulj(x4, {wd.x, wd.y});
      }
      dft5(x0,x1,x2,x3,x4, -1.f, y0,y1,y2,y3,y4);
    }
    z[base]      = make_float2(y0.re, y0.im);
    z[base+st]   = make_float2(y1.re, y1.im);
    z[base+2*st] = make_float2(y2.re, y2.im);
    z[base+3*st] = make_float2(y3.re, y3.im);
    z[base+4*st] = make_float2(y4.re, y4.im);
  }
}

template<int M, bool FWD>
__device__ void r2_stage(float2* z, const float2* w128s, int tid, int nthr) {
  const int hStep = M/2;
  for (int bf = tid; bf < 8000; bf += nthr) {
    int row = bf >> 6, t = bf & 63;
    int blk = t / hStep, j = t - blk*hStep;
    int p1 = row*128 + blk*M + j, p2 = p1 + hStep;
    float2 va = z[p1], vb = z[p2];
    cpx a = {va.x, va.y}, b = {vb.x, vb.y};
    float2 wf = w128s[j*(128/M)];
    cpx w = {wf.x, wf.y};
    if (FWD) {
      cpx s = cadd(a,b);
      cpx d = cmul(csub(a,b), w);
      z[p1] = make_float2(s.re, s.im);
      z[p2] = make_float2(d.re, d.im);
    } else {
      cpx tt = cmulj(b, w);
      cpx s = cadd(a,tt), d = csub(a,tt);
      z[p1] = make_float2(s.re, s.im);
      z[p2] = make_float2(d.re, d.im);
    }
  }
}

template<bool FWD>
__device__ void twiddle_pass(float2* z, int tid, int nthr) {
  for (int e = tid; e < 16000; e += nthr) {
    int row = e >> 7, col = e & 127;
    int k1 = dr5i(row);
    int m = col * k1;                          // < 16000, no mod needed
    float ph = (float)m * (6.283185307179586f / 16000.f);
    float s, c;
    __sincosf(ph, &s, &c);
    cpx w = {c, FWD ? -s : s};
    float2 v2 = z[e];
    cpx v = cmul({v2.x, v2.y}, w);
    z[e] = make_float2(v.re, v.im);
  }
}

__device__ void spectral_multiply(float2* z, int tid, int nthr) {
  for (int idx = tid; idx < 8001; idx += nthr) {
    int k1, k2, k1p, k2p;
    if (idx < 7936) { k1 = 1 + (idx >> 7); k2 = idx & 127; k1p = 125 - k1; k2p = 127 - k2; }
    else            { k1 = 0; k2 = idx - 7936; k1p = 0;    k2p = (128 - k2) & 127; }
    int pos  = dr5i(k1)*128  + br7i(k2);
    int posp = dr5i(k1p)*128 + br7i(k2p);
    float2 vk = z[pos], vm = z[posp];
    cpx Zk = {vk.x, vk.y}, Zm = {vm.x, vm.y};
    cpx F1 = {0.5f*(Zk.re + Zm.re), 0.5f*(Zk.im - Zm.im)};
    cpx F2 = {0.5f*(Zk.im + Zm.im), 0.5f*(Zm.re - Zk.re)};
    cpx Y = cmul(F1, F2);
    z[pos]  = make_float2(Y.re,  Y.im);
    z[posp] = make_float2(Y.re, -Y.im);   // self-pairs: Y.im == 0, benign
  }
}

__device__ void fft_convolve(float2* z, const float2* w128s, const float2* w125s,
                             int tid, int nthr) {
  r5_stage<125,true>(z,w125s,tid,nthr); __syncthreads();
  r5_stage<25, true>(z,w125s,tid,nthr); __syncthreads();
  r5_stage<5,  true>(z,w125s,tid,nthr); __syncthreads();
  twiddle_pass<true>(z,tid,nthr);       __syncthreads();
  r2_stage<128,true>(z,w128s,tid,nthr); __syncthreads();
  r2_stage<64, true>(z,w128s,tid,nthr); __syncthreads();
  r2_stage<32, true>(z,w128s,tid,nthr); __syncthreads();
  r2_stage<16, true>(z,w128s,tid,nthr); __syncthreads();
  r2_stage<8,  true>(z,w128s,tid,nthr); __syncthreads();
  r2_stage<4,  true>(z,w128s,tid,nthr); __syncthreads();
  r2_stage<2,  true>(z,w128s,tid,nthr); __syncthreads();
  spectral_multiply(z,tid,nthr);        __syncthreads();
  r2_stage<2,  false>(z,w128s,tid,nthr); __syncthreads();
  r2_stage<4,  false>(z,w128s,tid,nthr); __syncthreads();
  r2_stage<8,  false>(z,w128s,tid,nthr); __syncthreads();
  r2_stage<16, false>(z,w128s,tid,nthr); __syncthreads();
  r2_stage<32, false>(z,w128s,tid,nthr); __syncthreads();
  r2_stage<64, false>(z,w128s,tid,nthr); __syncthreads();
  r2_stage<128,false>(z,w128s,tid,nthr); __syncthreads();
  twiddle_pass<false>(z,tid,nthr);       __syncthreads();
  r5_stage<5,  false>(z,w125s,tid,nthr); __syncthreads();
  r5_stage<25, false>(z,w125s,tid,nthr); __syncthreads();
  r5_stage<125,false>(z,w125s,tid,nthr); __syncthreads();
}

__device__ __forceinline__ float block_sum(float v, float* red, int tid, int nthr) {
  #pragma unroll
  for (int off = 32; off > 0; off >>= 1) v += __shfl_down(v, off);
  if ((tid & 63) == 0) red[tid >> 6] = v;
  __syncthreads();
  if (tid == 0) {
    float s = 0.f;
    for (int w = 0; w < (nthr >> 6); ++w) s += red[w];
    red[0] = s;
  }
  __syncthreads();
  return red[0];
}

__device__ __forceinline__ void init_twiddle_tables(float2* w128s, float2* w125s, int tid) {
  if (tid < 64) {
    float s, c; sincosf((float)tid * (6.283185307179586f/128.f), &s, &c);
    w128s[tid] = make_float2(c, -s);
  } else if (tid < 164) {
    int t = tid - 64;
    float s, c; sincosf((float)t * (6.283185307179586f/125.f), &s, &c);
    w125s[t] = make_float2(c, -s);
  }
}

// ---------------- K0: avgpool(txt) -> txt_p (32,2048) ----------------
__global__ void k_txtpool(const float* __restrict__ txt, float* __restrict__ txtp) {
  int idx = blockIdx.x*256 + threadIdx.x;      // exactly 32*2048 threads
  int b = idx >> 11, w = idx & 2047;
  const float* t = txt + (size_t)b*SEQ*CDIM;
  float s = 0.f;
  #pragma unroll
  for (int r = 0; r < 2; ++r)
    #pragma unroll
    for (int dc = -1; dc <= 1; ++dc) {
      int c = w + dc;
      if (c >= 0 && c < CDIM) s += t[r*CDIM + c];
    }
  txtp[idx] = s * (1.0f/9.0f);
}

// ---------------- K1: CBP #1 -> bf16 signed_sqrt values + row norm ----------------
__global__ void __launch_bounds__(K1T) k_cbp1(
    const float* __restrict__ txtp, const float* __restrict__ img,
    const int* __restrict__ h1a, const int* __restrict__ s1a,
    const int* __restrict__ h2a, const int* __restrict__ s2a,
    __hip_bfloat16* __restrict__ ss1, float* __restrict__ norm1) {
  __shared__ float2 zbuf[16000];
  __shared__ float2 w128s[64];
  __shared__ float2 w125s[100];
  __shared__ float red[8];
  int tid = threadIdx.x;
  int r = blockIdx.x;
  int b = r / NPOS, p = r % NPOS;
  init_twiddle_tables(w128s, w125s, tid);
  for (int n = tid; n < 16000; n += K1T) zbuf[n] = make_float2(0.f, 0.f);
  __syncthreads();
  const float* tp = txtp + b*CDIM;
  for (int i = tid; i < CDIM; i += K1T) {
    int idx = (49*i + p) & (CDIM-1);
    float a = (float)s1a[i] * tp[idx];
    atomicAdd(&zbuf[h1a[i]].x, a);
    float bb = (float)s2a[i] * img[((size_t)b*CDIM + i)*NPOS + p];
    atomicAdd(&zbuf[h2a[i]].y, bb);
  }
  __syncthreads();
  fft_convolve(zbuf, w128s, w125s, tid, K1T);
  const float inv = 1.0f/16000.0f;
  float sumsq = 0.f;
  for (int n = tid; n < 16000; n += K1T) {
    float v = zbuf[n].x * inv;
    float o = copysignf(sqrtf(fabsf(v)), v);
    ss1[(size_t)r*D_MCB + n] = __float2bfloat16(o);
    sumsq += o*o;
  }
  float tot = block_sum(sumsq, red, tid, K1T);
  if (tid == 0) norm1[r] = fmaxf(sqrtf(tot), 1e-12f);
}

// ---------------- cast conv1_w (512x16000) fp32 -> bf16 ----------------
__global__ void k_castw1(const float* __restrict__ w, __hip_bfloat16* __restrict__ wb) {
  int i = (blockIdx.x*256 + threadIdx.x)*4;   // grid covers 512*16000/4
  float4 v = *(const float4*)(w + i);
  __hip_bfloat16 t[4] = {__float2bfloat16(v.x), __float2bfloat16(v.y),
                         __float2bfloat16(v.z), __float2bfloat16(v.w)};
  *(uint2*)(wb + i) = *(uint2*)t;
}

// ---------------- K2: conv1 via bf16 MFMA, split-K=10 partials ----------------
// grid (13, 4, 10), block 256 = 4 waves (2x2). tile 128x128, BK=32.
// LDS: A/B tiles [128 rows][32 k] bf16, row = 64B = 4 x 16B slots.
// Bank swizzle: logical slot s stored at phys slot s ^ ((row>>1)&3) (involution),
// applied on the GLOBAL source addr (global_load_lds writes linearly, rule #21).
#define C1_MT 13
#define C1_KSPLIT 10
#define C1_KSPAN 1600
__global__ void __launch_bounds__(256) k_conv1_mfma(
    const __hip_bfloat16* __restrict__ ss1, const __hip_bfloat16* __restrict__ w1b,
    float* __restrict__ part) {
  __shared__ short Abuf[128*32];
  __shared__ short Bbuf[128*32];
  const int tid = threadIdx.x;
  const int w = tid >> 6, l = tid & 63;
  const int wr = w >> 1, wc = w & 1;
  const int m0 = blockIdx.x*128, n0 = blockIdx.y*128;
  const int ksl = blockIdx.z;
  const size_t kbase = (size_t)ksl*C1_KSPAN;

  // staging source pointers (2 instrs each for A and B), constant except k
  const __hip_bfloat16* gA[2]; const __hip_bfloat16* gB[2];
  char* lA[2]; char* lB[2];
  #pragma unroll
  for (int i = 0; i < 2; ++i) {
    int r_loc = w*32 + i*16 + (l>>2);
    int s_log = (l&3) ^ ((r_loc>>1)&3);
    int gmr = m0 + r_loc; if (gmr > 1567) gmr = 1567;
    gA[i] = ss1 + (size_t)gmr*D_MCB + kbase + s_log*8;
    gB[i] = w1b + (size_t)(n0 + r_loc)*D_MCB + kbase + s_log*8;
    lA[i] = (char*)Abuf + w*2048 + i*1024 + l*16;
    lB[i] = (char*)Bbuf + w*2048 + i*1024 + l*16;
  }
  // fragment LDS byte offsets (constant over k loop)
  int offA[4], offB[4];
  #pragma unroll
  for (int f = 0; f < 4; ++f) {
    int rA = wr*64 + f*16 + (l&15);
    offA[f] = rA*64 + (((l>>4) ^ ((rA>>1)&3))<<4);
    int rB = wc*64 + f*16 + (l&15);
    offB[f] = rB*64 + (((l>>4) ^ ((rB>>1)&3))<<4);
  }
  f32x4 zero = {0.f,0.f,0.f,0.f};
  f32x4 acc[4][4];
  #pragma unroll
  for (int i = 0; i < 4; ++i)
    #pragma unroll
    for (int j = 0; j < 4; ++j) acc[i][j] = zero;

  for (int ks = 0; ks < C1_KSPAN/32; ++ks) {
    const int ko = ks*32;
    #pragma unroll
    for (int i = 0; i < 2; ++i) {
      __builtin_amdgcn_global_load_lds(
        (const __attribute__((address_space(1))) void*)(gA[i] + ko),
        (__attribute__((address_space(3))) void*)lA[i], 16, 0, 0);
      __builtin_amdgcn_global_load_lds(
        (const __attribute__((address_space(1))) void*)(gB[i] + ko),
        (__attribute__((address_space(3))) void*)lB[i], 16, 0, 0);
    }
    __syncthreads();   // drains vmcnt before barrier (compiler-inserted)
    short8 af[4], bf[4];
    #pragma unroll
    for (int f = 0; f < 4; ++f) {
      af[f] = *(const short8*)((const char*)Abuf + offA[f]);
      bf[f] = *(const short8*)((const char*)Bbuf + offB[f]);
    }
    #pragma unroll
    for (int i = 0; i < 4; ++i)
      #pragma unroll
      for (int j = 0; j < 4; ++j)
        acc[i][j] = __builtin_amdgcn_mfma_f32_16x16x32_bf16(af[i], bf[j], acc[i][j], 0, 0, 0);
    __syncthreads();   // protect LDS before next stage
  }

  float* pb = part + (size_t)ksl*(1568*512);
  #pragma unroll
  for (int i = 0; i < 4; ++i) {
    #pragma unroll
    for (int reg = 0; reg < 4; ++reg) {
      int gm = m0 + wr*64 + i*16 + (l>>4)*4 + reg;
      if (gm < 1568) {
        #pragma unroll
        for (int j = 0; j < 4; ++j) {
          int gn = n0 + wc*64 + j*16 + (l&15);
          pb[(size_t)gm*512 + gn] = acc[i][j][reg];
        }
      }
    }
  }
}

// reduce split-K partials, /norm, +bias, relu
__global__ void k_conv1_epi(const float* __restrict__ part, const float* __restrict__ norm1,
                            const float* __restrict__ b1, float* __restrict__ out1) {
  int t = blockIdx.x*256 + threadIdx.x;       // 1568*512 threads
  int m = t >> 9, n = t & 511;
  float s = 0.f;
  #pragma unroll
  for (int k = 0; k < C1_KSPLIT; ++k) s += part[(size_t)k*(1568*512) + t];
  out1[t] = fmaxf(s/norm1[m] + b1[n], 0.f);
}

// ---------------- K3: conv2 + softmax(49) + attention-weighted pooling -> res ------
__global__ void __launch_bounds__(256) k_attn(
    const float* __restrict__ out1, const float* __restrict__ w2,
    const float* __restrict__ b2, const float* __restrict__ img,
    float* __restrict__ res) {
  __shared__ float s_lds[NPOS];
  __shared__ float att[NPOS];
  int b = blockIdx.x, tid = threadIdx.x;
  int wave = tid >> 6, lane = tid & 63;
  for (int p = wave; p < NPOS; p += 4) {
    const float* row = out1 + (size_t)(b*NPOS + p)*NC1;
    float acc = 0.f;
    for (int o = lane; o < NC1; o += 64) acc += row[o]*w2[o];
    #pragma unroll
    for (int off = 32; off > 0; off >>= 1) acc += __shfl_down(acc, off);
    if (lane == 0) s_lds[p] = acc + b2[0];
  }
  __syncthreads();
  if (tid < 64) {
    float v = (tid < NPOS) ? s_lds[tid] : -INFINITY;
    float mx = v;
    #pragma unroll
    for (int off = 32; off > 0; off >>= 1) mx = fmaxf(mx, __shfl_xor(mx, off));
    float e = (tid < NPOS) ? expf(v - mx) : 0.f;
    float se = e;
    #pragma unroll
    for (int off = 32; off > 0; off >>= 1) se += __shfl_xor(se, off);
    if (tid < NPOS) att[tid] = e / se;
  }
  __syncthreads();
  const float* ib = img + (size_t)b*CDIM*NPOS;
  for (int c = tid; c < CDIM; c += 256) {
    float acc = 0.f;
    for (int p = 0; p < NPOS; ++p) acc += att[p]*ib[(size_t)p*CDIM + c];
    res[b*CDIM + c] = acc;
  }
}

// ---------------- K4: CBP #2 (32 rows), signed_sqrt + norm ----------------
__global__ void __launch_bounds__(K1T) k_cbp2(
    const float* __restrict__ txtp, const float* __restrict__ res,
    const int* __restrict__ h1b, const int* __restrict__ s1b,
    const int* __restrict__ h2b, const int* __restrict__ s2b,
    float* __restrict__ fin_ss, float* __restrict__ norm2) {
  __shared__ float2 zbuf[16000];
  __shared__ float2 w128s[64];
  __shared__ float2 w125s[100];
  __shared__ float red[8];
  int tid = threadIdx.x;
  int b = blockIdx.x;
  init_twiddle_tables(w128s, w125s, tid);
  for (int n = tid; n < 16000; n += K1T) zbuf[n] = make_float2(0.f, 0.f);
  __syncthreads();
  for (int i = tid; i < CDIM; i += K1T) {
    atomicAdd(&zbuf[h1b[i]].x, (float)s1b[i] * txtp[b*CDIM + i]);
    atomicAdd(&zbuf[h2b[i]].y, (float)s2b[i] * res[b*CDIM + i]);
  }
  __syncthreads();
  fft_convolve(zbuf, w128s, w125s, tid, K1T);
  const float inv = 1.0f/16000.0f;
  float sumsq = 0.f;
  for (int n = tid; n < 16000; n += K1T) {
    float v = zbuf[n].x * inv;
    float o = copysignf(sqrtf(fabsf(v)), v);
    fin_ss[(size_t)b*D_MCB + n] = o;
    sumsq += o*o;
  }
  float tot = block_sum(sumsq, red, tid, K1T);
  if (tid == 0) norm2[b] = fmaxf(sqrtf(tot), 1e-12f);
}

// ---------------- K5: final linear (32x16000)x(3000x16000)^T /norm + bias ----------
__global__ void k_out_init(const float* __restrict__ lin2b, float* __restrict__ out) {
  int i = blockIdx.x*256 + threadIdx.x;
  if (i < NBATCH*NOUT) out[i] = lin2b[i % NOUT];
}

#define K5BK 40
__global__ void __launch_bounds__(256) k_lin2(
    const float* __restrict__ fin_ss, const float* __restrict__ norm2,
    const float* __restrict__ w, float* __restrict__ out) {
  __shared__ float Ws[K5BK*128];   // [kk][o]
  __shared__ float Fs[32*44];      // [b][kk], padded
  int tid = threadIdx.x;
  int nt = blockIdx.x;             // 24 tiles of 128 outputs
  int kc = blockIdx.y;             // 8 chunks of 2000
  int o0 = nt*128;
  int kb = kc*2000;
  int tb = tid >> 5, to = tid & 31;
  float acc[4][4] = {};
  for (int ks = 0; ks < 2000; ks += K5BK) {
    for (int q = tid; q < 1280; q += 256) {
      int wrow = q / 10, wq = q % 10;
      int orow = o0 + wrow; if (orow > NOUT-1) orow = NOUT-1;
      float4 v = *(const float4*)(w + (size_t)orow*D_MCB + kb + ks + wq*4);
      Ws[(wq*4+0)*128 + wrow] = v.x;
      Ws[(wq*4+1)*128 + wrow] = v.y;
      Ws[(wq*4+2)*128 + wrow] = v.z;
      Ws[(wq*4+3)*128 + wrow] = v.w;
    }
    for (int q = tid; q < 320; q += 256) {
      int fr = q / 10, fq = q % 10;
      float4 v = *(const float4*)(fin_ss + (size_t)fr*D_MCB + kb + ks + fq*4);
      *(float4*)&Fs[fr*44 + fq*4] = v;
    }
    __syncthreads();
    #pragma unroll 8
    for (int kk = 0; kk < K5BK; ++kk) {
      float fv[4];
      #pragma unroll
      for (int i = 0; i < 4; ++i) fv[i] = Fs[(tb*4+i)*44 + kk];
      float4 wv = *(float4*)&Ws[kk*128 + to*4];
      #pragma unroll
      for (int i = 0; i < 4; ++i) {
        acc[i][0] += fv[i]*wv.x; acc[i][1] += fv[i]*wv.y;
        acc[i][2] += fv[i]*wv.z; acc[i][3] += fv[i]*wv.w;
      }
    }
    __syncthreads();
  }
  #pragma unroll
  for (int i = 0; i < 4; ++i) {
    int bb = tb*4 + i;
    float nrm = norm2[bb];
    #pragma unroll
    for (int j = 0; j < 4; ++j) {
      int o = o0 + to*4 + j;
      if (o < NOUT) atomicAdd(&out[bb*NOUT + o], acc[i][j]/nrm);
    }
  }
}

// ---------------- launch ----------------
extern "C" void kernel_launch(void* const* d_in, const int* in_sizes, int n_in,
                              void* d_out, int out_size, void* d_ws, size_t ws_size,
                              hipStream_t stream) {
  (void)in_sizes; (void)n_in; (void)out_size; (void)ws_size;
  const float* txt    = (const float*)d_in[0];
  const float* img    = (const float*)d_in[1];
  const float* conv1w = (const float*)d_in[2];
  const float* conv1b = (const float*)d_in[3];
  const float* conv2w = (const float*)d_in[4];
  const float* conv2b = (const float*)d_in[5];
  const float* lin2w  = (const float*)d_in[6];
  const float* lin2b  = (const float*)d_in[7];
  const int* h1a = (const int*)d_in[8];  const int* s1a = (const int*)d_in[9];
  const int* h2a = (const int*)d_in[10]; const int* s2a = (const int*)d_in[11];
  const int* h1b = (const int*)d_in[12]; const int* s1b = (const int*)d_in[13];
  const int* h2b = (const int*)d_in[14]; const int* s2b = (const int*)d_in[15];
  float* out = (float*)d_out;
  char* ws = (char*)d_ws;
  // workspace layout (16B aligned), total ~99.6 MiB
  float*           txtp   = (float*)(ws + 0);          //   262,144 B
  float*           norm1  = (float*)(ws + 262144);     //     6,272 B
  float*           resb   = (float*)(ws + 268416);     //   262,144 B
  float*           norm2  = (float*)(ws + 530560);     //       128 B
  float*           fin_ss = (float*)(ws + 530688);     // 2,048,000 B
  float*           out1   = (float*)(ws + 2578688);    // 3,211,264 B
  __hip_bfloat16*  ss1    = (__hip_bfloat16*)(ws + 5789952);   // 50,176,000 B
  __hip_bfloat16*  w1b    = (__hip_bfloat16*)(ws + 55965952);  // 16,384,000 B
  float*           part   = (float*)(ws + 72349952);           // 32,112,640 B

  k_txtpool<<<dim3(256), dim3(256), 0, stream>>>(txt, txtp);
  k_castw1<<<dim3(NC1*D_MCB/1024), dim3(256), 0, stream>>>(conv1w, w1b);
  k_cbp1<<<dim3(NBATCH*NPOS), dim3(K1T), 0, stream>>>(txtp, img, h1a, s1a, h2a, s2a, ss1, norm1);
  k_conv1_mfma<<<dim3(C1_MT, 4, C1_KSPLIT), dim3(256), 0, stream>>>(ss1, w1b, part);
  k_conv1_epi<<<dim3(1568*512/256), dim3(256), 0, stream>>>(part, norm1, conv1b, out1);
  k_attn<<<dim3(NBATCH), dim3(256), 0, stream>>>(out1, conv2w, conv2b, img, resb);
  k_cbp2<<<dim3(NBATCH), dim3(K1T), 0, stream>>>(txtp, resb, h1b, s1b, h2b, s2b, fin_ss, norm2);
  k_out_init<<<dim3((NBATCH*NOUT + 255)/256), dim3(256), 0, stream>>>(lin2b, out);
  k_lin2<<<dim3(24, 8), dim3(256), 0, stream>>>(fin_ss, norm2, lin2w, out);
}